// Round 16
// baseline (203.899 us; speedup 1.0000x reference)
//
#include <hip/hip_runtime.h>

#define NNODES 20000
#define NEDGES 320000
#define ELLW 64                           // ELL row width (max degree ~40 for this graph)
#define DCAP 64                           // logit cache == ELL width (no overflow path)

typedef __attribute__((ext_vector_type(4))) float f32x4;
typedef _Float16 f16x4 __attribute__((ext_vector_type(4)));
typedef _Float16 f16x8 __attribute__((ext_vector_type(8)));

__device__ __forceinline__ float leaky(float x) { return x > 0.f ? x : 0.2f * x; }
__device__ __forceinline__ float elu(float x) { return x > 0.f ? x : expm1f(x); }

// async 16B global->LDS (DMA; zero VGPR cost; compiler cannot serialize it)
__device__ __forceinline__ void gll16(const ushort* g, ushort* l) {
  __builtin_amdgcn_global_load_lds((const __attribute__((address_space(1))) void*)g,
                                   (__attribute__((address_space(3))) void*)l, 16, 0, 0);
}

// ---------------- weights -> f16 [OC][K] fragment order; zeroes fill ----------------
__device__ __forceinline__ void prep_w_one(const float* __restrict__ w, _Float16* __restrict__ th,
                                           int K, int OC, int idx) {
  int KC = K / 32;
  int oc = idx / KC, c = idx % KC;
  _Float16 h[32];
#pragma unroll
  for (int r = 0; r < 32; r++) {
    int p = (r < 16) ? ((r >> 2) * 8 + (r & 3)) : (((r - 16) >> 2) * 8 + 4 + (r & 3));
    h[p] = (_Float16)w[(size_t)(c * 32 + r) * OC + oc];
  }
  _Float16* ho = th + (size_t)oc * K + c * 32;
#pragma unroll
  for (int q = 0; q < 4; q++) *(f16x8*)&ho[q * 8] = *(f16x8*)&h[q * 8];
}

__global__ void k_prep_w3z(const float* __restrict__ w0, const float* __restrict__ w1,
                           const float* __restrict__ w2,
                           _Float16* __restrict__ th0, _Float16* __restrict__ th1,
                           _Float16* __restrict__ th2, int* __restrict__ fill) {
  int i = blockIdx.x * blockDim.x + threadIdx.x;
  if (i < NNODES) fill[i] = 0;
  if (i < 1024) prep_w_one(w0, th0, 128, 256, i);
  else if (i < 3072) prep_w_one(w1, th1, 256, 256, i - 1024);
  else if (i < 3584) prep_w_one(w2, th2, 256, 64, i - 3072);
}

// ---------------- fp32 -> f16 fragment-packed + ELL adjacency build (one pass) ----------------
__global__ void k_cvt_ell(const float* __restrict__ a, _Float16* __restrict__ Ap, int total,
                          const int* __restrict__ srcA, const int* __restrict__ dstA,
                          int* __restrict__ fill, int* __restrict__ ell, int e) {
  int i = blockIdx.x * blockDim.x + threadIdx.x;
  if (i < e) {
    int d = dstA[i];
    int k = atomicAdd(&fill[d], 1);
    if (k < ELLW) ell[d * ELLW + k] = srcA[i];
  }
  if (i >= total) return;
  const float* src = a + (size_t)i * 32;
  _Float16 h[32];
#pragma unroll
  for (int r = 0; r < 32; r++) {
    int p = (r < 16) ? ((r >> 2) * 8 + (r & 3)) : (((r - 16) >> 2) * 8 + 4 + (r & 3));
    h[p] = (_Float16)src[r];
  }
  _Float16* ho = Ap + (size_t)i * 32;
#pragma unroll
  for (int q = 0; q < 4; q++) *(f16x8*)&ho[q * 8] = *(f16x8*)&h[q * 8];
}

// ---------------- MFMA GEMM (single f16), async LDS double-buffer, fused asd epilogue ----------------
template <int K, int NCT, int HEADS>
__global__ __launch_bounds__(256) void k_gemm_mfma(const ushort* __restrict__ Ah, const ushort* __restrict__ Bh,
                                                   const float* __restrict__ asrc, const float* __restrict__ adst,
                                                   _Float16* __restrict__ H, float* __restrict__ a_s,
                                                   float* __restrict__ a_d, int M, int OC) {
  constexpr int BM = 64, BN = NCT * 64, NC = K / 32;
  constexpr int BOFF = 2048;
  constexpr int BUFE = BOFF + BN * 32;
  __shared__ ushort sb0[BUFE], sb1[BUFE];
  __shared__ float sh_s[4][64], sh_d[4][64];
  int w = threadIdx.x >> 6, l = threadIdx.x & 63;
  int n0 = blockIdx.x * BM;
  int cw = blockIdx.y * BN + w * (NCT * 16);
  int lr = l & 15;

  int q = l & 3;
  int srow = 16 * w + (l >> 2);
  int sgrow = min(n0 + srow, M - 1);
  int gA = q ^ ((srow >> 1) & 3);
  const ushort* aH = Ah + (size_t)sgrow * K + gA * 8;
  const ushort* bH[NCT];
  int colb[NCT];
#pragma unroll
  for (int i = 0; i < NCT; i++) {
    colb[i] = 16 * NCT * w + 16 * i;
    int sc = colb[i] + (l >> 2);
    int gB = q ^ ((sc >> 1) & 3);
    bH[i] = Bh + (size_t)(blockIdx.y * BN + sc) * K + gB * 8;
  }

#define STAGE(buf, c)                                              \
  {                                                                \
    gll16(aH + (c) * 32, &buf[w * 512]);                           \
    _Pragma("unroll") for (int i = 0; i < NCT; i++)                \
      gll16(bH[i] + (c) * 32, &buf[BOFF + colb[i] * 32]);          \
  }

  f32x4 acc[4][NCT];
#pragma unroll
  for (int r = 0; r < 4; r++)
#pragma unroll
    for (int t = 0; t < NCT; t++) acc[r][t] = (f32x4){0.f, 0.f, 0.f, 0.f};

#define COMP(buf)                                                                   \
  {                                                                                 \
    f16x8 bhf[NCT];                                                                 \
    _Pragma("unroll") for (int t = 0; t < NCT; t++) {                               \
      int bcol = 16 * NCT * w + 16 * t + lr;                                        \
      int gb = (l >> 4) ^ ((bcol >> 1) & 3);                                        \
      bhf[t] = *(const f16x8*)&buf[BOFF + bcol * 32 + gb * 8];                      \
    }                                                                               \
    _Pragma("unroll") for (int r = 0; r < 4; r++) {                                 \
      int arow = 16 * r + lr;                                                       \
      int ga = (l >> 4) ^ ((arow >> 1) & 3);                                        \
      f16x8 ahf = *(const f16x8*)&buf[arow * 32 + ga * 8];                          \
      _Pragma("unroll") for (int t = 0; t < NCT; t++)                               \
        acc[r][t] = __builtin_amdgcn_mfma_f32_16x16x32_f16(ahf, bhf[t], acc[r][t], 0, 0, 0); \
    }                                                                               \
  }

  ushort* cur = sb0;
  ushort* nxt = sb1;
  STAGE(cur, 0);
  __syncthreads();
  for (int c = 0; c < NC; ++c) {
    if (c + 1 < NC) STAGE(nxt, c + 1);
    COMP(cur);
    __syncthreads();
    ushort* tmp = cur; cur = nxt; nxt = tmp;
  }
#undef STAGE
#undef COMP

#pragma unroll
  for (int r = 0; r < 4; r++)
#pragma unroll
    for (int t = 0; t < NCT; t++)
#pragma unroll
      for (int reg = 0; reg < 4; reg++) {
        int row = n0 + 16 * r + (l >> 4) * 4 + reg;
        if (row < M) H[(size_t)row * OC + cw + 16 * t + lr] = (_Float16)acc[r][t][reg];
      }

  float asv[NCT], adv[NCT];
#pragma unroll
  for (int t = 0; t < NCT; t++) {
    asv[t] = asrc[cw + 16 * t + lr];
    adv[t] = adst[cw + 16 * t + lr];
  }
#pragma unroll
  for (int r = 0; r < 4; r++) {
#pragma unroll
    for (int reg = 0; reg < 4; reg++) {
      float ps = 0.f, pd = 0.f;
#pragma unroll
      for (int t = 0; t < NCT; t++) {
        ps += acc[r][t][reg] * asv[t];
        pd += acc[r][t][reg] * adv[t];
      }
#pragma unroll
      for (int mask = 1; mask < 16; mask <<= 1) {
        ps += __shfl_xor(ps, mask, 64);
        pd += __shfl_xor(pd, mask, 64);
      }
      int rl = 16 * r + (l >> 4) * 4 + reg;
      if (lr == 0) { sh_s[w][rl] = ps; sh_d[w][rl] = pd; }
    }
  }
  __syncthreads();
  int tid = threadIdx.x;
  if (HEADS == 4) {
    if (tid < 128) {
      int rr = tid & 63, hl = tid >> 6;
      int row = n0 + rr;
      if (row < M) {
        int hidx = row * 4 + blockIdx.y * 2 + hl;
        a_s[hidx] = sh_s[2 * hl][rr] + sh_s[2 * hl + 1][rr];
        a_d[hidx] = sh_d[2 * hl][rr] + sh_d[2 * hl + 1][rr];
      }
    }
  } else {
    if (tid < 64) {
      int row = n0 + tid;
      if (row < M) {
        a_s[row] = sh_s[0][tid] + sh_s[1][tid] + sh_s[2][tid] + sh_s[3][tid];
        a_d[row] = sh_d[0][tid] + sh_d[1][tid] + sh_d[2][tid] + sh_d[3][tid];
      }
    }
  }
}

// ---------------- fused softmax + gather (per-head): ELL rows, 4 edge-groups of 16 lanes ----------
// grid.y = head. Per-head working set h-slice = 2.5MB < 4MB per-XCD L2; heads processed in
// dispatch phases -> gathers mostly L2-hit. Wave = 1 node, 1 head; lanes (grp=l>>4, cl=l&15).
__global__ __launch_bounds__(256) void k_gat4h(const _Float16* __restrict__ h, const float* __restrict__ a_s,
                                               const float* __restrict__ a_d, const int* __restrict__ fill,
                                               const int* __restrict__ ell, const float* __restrict__ bias,
                                               _Float16* __restrict__ Ap) {
  __shared__ float elds[4][DCAP];
  int wid = threadIdx.x >> 6, l = threadIdx.x & 63;
  int n = blockIdx.x * 4 + wid;
  if (n >= NNODES) return;
  int hd = blockIdx.y;
  int grp = l >> 4, cl = l & 15;
  int jb = n * ELLW;
  int cnt = min(fill[n], ELLW);
  int je = jb + cnt;
  float ad = a_d[n * 4 + hd];
  float es = leaky(a_s[n * 4 + hd] + ad);
  float m = -1e30f, s = 0.f;
  if (l == 0) { m = es; s = 1.f; }
  for (int j = jb + l; j < je; j += 64) {
    float e = leaky(a_s[ell[j] * 4 + hd] + ad);
    elds[wid][j - jb] = e;
    float nm = fmaxf(m, e);
    s = s * __expf(m - nm) + __expf(e - nm);
    m = nm;
  }
#pragma unroll
  for (int mask = 1; mask < 64; mask <<= 1) {
    float m2 = __shfl_xor(m, mask, 64);
    float s2 = __shfl_xor(s, mask, 64);
    float nm = fmaxf(m, m2);
    s = s * __expf(m - nm) + s2 * __expf(m2 - nm);
    m = nm;
  }
  __asm__ volatile("" ::: "memory");   // LDS writes ordered before reads (same wave)
  float inv = 1.f / s;
  float sa = __expf(es - m) * inv;

  const _Float16* hh = h + hd * 64;    // head slice base
  float acc[4] = {0.f, 0.f, 0.f, 0.f};
  f16x4 hv = *(const f16x4*)&hh[(size_t)n * 256 + cl * 4];
  if (grp == 0) {
#pragma unroll
    for (int i = 0; i < 4; i++) acc[i] = sa * (float)hv[i];
  }
  int j = jb;
  for (; j + 7 < je; j += 8) {    // 2 group-passes -> 8 edges in flight
    int e0 = j + grp, e1 = j + 4 + grp;
    int s0 = ell[e0], s1 = ell[e1];
    float a0 = __expf(elds[wid][e0 - jb] - m) * inv;
    float a1 = __expf(elds[wid][e1 - jb] - m) * inv;
    f16x4 v0 = *(const f16x4*)&hh[(size_t)s0 * 256 + cl * 4];
    f16x4 v1 = *(const f16x4*)&hh[(size_t)s1 * 256 + cl * 4];
#pragma unroll
    for (int i = 0; i < 4; i++) acc[i] += a0 * (float)v0[i] + a1 * (float)v1[i];
  }
  for (; j + 3 < je; j += 4) {
    int e0 = j + grp;
    int s0 = ell[e0];
    float a0 = __expf(elds[wid][e0 - jb] - m) * inv;
    f16x4 v0 = *(const f16x4*)&hh[(size_t)s0 * 256 + cl * 4];
#pragma unroll
    for (int i = 0; i < 4; i++) acc[i] += a0 * (float)v0[i];
  }
  if (j + grp < je) {   // tail: groups 0..r-1 take one edge each
    int e0 = j + grp;
    int s0 = ell[e0];
    float a0 = __expf(elds[wid][e0 - jb] - m) * inv;
    f16x4 v0 = *(const f16x4*)&hh[(size_t)s0 * 256 + cl * 4];
#pragma unroll
    for (int i = 0; i < 4; i++) acc[i] += a0 * (float)v0[i];
  }
  // combine the 4 edge-groups (channels identical across groups)
#pragma unroll
  for (int i = 0; i < 4; i++) {
    acc[i] += __shfl_xor(acc[i], 16, 64);
    acc[i] += __shfl_xor(acc[i], 32, 64);
  }
  if (l < 16) {
    // channels c0 = hd*64 + cl*4 -> packed f16 fragment layout for next GEMM
    int c0 = hd * 64 + cl * 4;
    int k = c0 & 31;
    size_t base = (size_t)n * 256 + (c0 >> 5) * 32 + ((k < 16) ? (k >> 2) * 8 : (((k - 16) >> 2) * 8 + 4));
    float4 b = *(const float4*)&bias[c0];
    f16x4 pk;
    pk[0] = (_Float16)elu(acc[0] + b.x);
    pk[1] = (_Float16)elu(acc[1] + b.y);
    pk[2] = (_Float16)elu(acc[2] + b.z);
    pk[3] = (_Float16)elu(acc[3] + b.w);
    *(f16x4*)&Ap[base] = pk;
  }
}

// ---------------- fused softmax + gather + MLP (1 head): ELL rows, 4 edge-groups ----------------
__global__ __launch_bounds__(256) void k_gat1(const _Float16* __restrict__ h, const float* __restrict__ a_s,
                                              const float* __restrict__ a_d, const int* __restrict__ fill,
                                              const int* __restrict__ ell, const float* __restrict__ bias,
                                              const float* __restrict__ w1, const float* __restrict__ b1,
                                              const float* __restrict__ w2, const float* __restrict__ b2,
                                              float* __restrict__ out) {
  __shared__ float elds[4][DCAP];
  __shared__ float sh[4][64];
  int wid = threadIdx.x >> 6, l = threadIdx.x & 63;
  int n = blockIdx.x * 4 + wid;
  int grp = l >> 4, cl = l & 15;
  float acc[4] = {0.f, 0.f, 0.f, 0.f};
  if (n < NNODES) {
    int jb = n * ELLW;
    int cnt = min(fill[n], ELLW);
    int je = jb + cnt;
    float ad = a_d[n];
    float es = leaky(a_s[n] + ad);
    float m = -1e30f, s = 0.f;
    if (l == 0) { m = es; s = 1.f; }
    for (int j = jb + l; j < je; j += 64) {
      float e = leaky(a_s[ell[j]] + ad);
      elds[wid][j - jb] = e;
      float nm = fmaxf(m, e);
      s = s * __expf(m - nm) + __expf(e - nm);
      m = nm;
    }
#pragma unroll
    for (int mask = 1; mask < 64; mask <<= 1) {
      float m2 = __shfl_xor(m, mask, 64);
      float s2 = __shfl_xor(s, mask, 64);
      float nm = fmaxf(m, m2);
      s = s * __expf(m - nm) + s2 * __expf(m2 - nm);
      m = nm;
    }
    __asm__ volatile("" ::: "memory");
    float inv = 1.f / s;
    float sa = __expf(es - m) * inv;
    f16x4 hv = *(const f16x4*)&h[(size_t)n * 64 + cl * 4];
    if (grp == 0) {
#pragma unroll
      for (int i = 0; i < 4; i++) acc[i] = sa * (float)hv[i];
    }
    int j = jb;
    for (; j + 7 < je; j += 8) {
      int e0 = j + grp, e1 = j + 4 + grp;
      int s0 = ell[e0], s1 = ell[e1];
      float a0 = __expf(elds[wid][e0 - jb] - m) * inv;
      float a1 = __expf(elds[wid][e1 - jb] - m) * inv;
      f16x4 v0 = *(const f16x4*)&h[(size_t)s0 * 64 + cl * 4];
      f16x4 v1 = *(const f16x4*)&h[(size_t)s1 * 64 + cl * 4];
#pragma unroll
      for (int i = 0; i < 4; i++) acc[i] += a0 * (float)v0[i] + a1 * (float)v1[i];
    }
    for (; j + 3 < je; j += 4) {
      int e0 = j + grp;
      int s0 = ell[e0];
      float a0 = __expf(elds[wid][e0 - jb] - m) * inv;
      f16x4 v0 = *(const f16x4*)&h[(size_t)s0 * 64 + cl * 4];
#pragma unroll
      for (int i = 0; i < 4; i++) acc[i] += a0 * (float)v0[i];
    }
    if (j + grp < je) {
      int e0 = j + grp;
      int s0 = ell[e0];
      float a0 = __expf(elds[wid][e0 - jb] - m) * inv;
      f16x4 v0 = *(const f16x4*)&h[(size_t)s0 * 64 + cl * 4];
#pragma unroll
      for (int i = 0; i < 4; i++) acc[i] += a0 * (float)v0[i];
    }
  }
#pragma unroll
  for (int i = 0; i < 4; i++) {
    acc[i] += __shfl_xor(acc[i], 16, 64);
    acc[i] += __shfl_xor(acc[i], 32, 64);
  }
  if (n < NNODES && l < 16) {
#pragma unroll
    for (int i = 0; i < 4; i++) sh[wid][cl * 4 + i] = elu(acc[i] + bias[cl * 4 + i]);
  }
  __syncthreads();
  float r = 0.f;
  if (l < 32 && n < NNODES) {
    r = b1[l];
#pragma unroll 8
    for (int k = 0; k < 64; k++) r += sh[wid][k] * w1[k * 32 + l];
    r = fmaxf(r, 0.f);
    r *= w2[l];
  }
  for (int mask = 16; mask >= 1; mask >>= 1) r += __shfl_xor(r, mask, 64);
  if (l == 0 && n < NNODES) out[n] = r + b2[0];
}

extern "C" void kernel_launch(void* const* d_in, const int* in_sizes, int n_in,
                              void* d_out, int out_size, void* d_ws, size_t ws_size,
                              hipStream_t stream) {
  const float* x    = (const float*)d_in[0];
  const int*   eidx = (const int*)d_in[1];
  const float* lin0 = (const float*)d_in[2];
  const float* as0  = (const float*)d_in[3];
  const float* ad0  = (const float*)d_in[4];
  const float* b0   = (const float*)d_in[5];
  const float* lin1 = (const float*)d_in[6];
  const float* as1  = (const float*)d_in[7];
  const float* ad1  = (const float*)d_in[8];
  const float* b1l  = (const float*)d_in[9];
  const float* lin2 = (const float*)d_in[10];
  const float* as2  = (const float*)d_in[11];
  const float* ad2  = (const float*)d_in[12];
  const float* b2l  = (const float*)d_in[13];
  const float* w1   = (const float*)d_in[14];
  const float* mb1  = (const float*)d_in[15];
  const float* w2   = (const float*)d_in[16];
  const float* mb2  = (const float*)d_in[17];
  float* outp = (float*)d_out;

  const int* srcA = eidx;
  const int* dstA = eidx + NEDGES;

  char* ws = (char*)d_ws;
  size_t o = 0;
  auto alloc = [&](size_t bytes) { size_t r = o; o += (bytes + 255) & ~255UL; return r; };
  _Float16* h16 = (_Float16*)(ws + alloc((size_t)NNODES * 256 * 2));
  _Float16* Ap  = (_Float16*)(ws + alloc((size_t)NNODES * 256 * 2));
  _Float16* wh0 = (_Float16*)(ws + alloc(128 * 256 * 2));
  _Float16* wh1 = (_Float16*)(ws + alloc(256 * 256 * 2));
  _Float16* wh2 = (_Float16*)(ws + alloc(256 * 64 * 2));
  float*  vas = (float*)(ws + alloc((size_t)NNODES * 4 * 4));
  float*  vad = (float*)(ws + alloc((size_t)NNODES * 4 * 4));
  int* fill = (int*)(ws + alloc(NNODES * 4));
  int* ell  = (int*)(ws + alloc((size_t)NNODES * ELLW * 4));

  // prep: weight pack + fill zero, then x pack + ELL adjacency build (2 dispatches total)
  k_prep_w3z<<<(NNODES + 255) / 256, 256, 0, stream>>>(lin0, lin1, lin2, wh0, wh1, wh2, fill);
  k_cvt_ell<<<(NEDGES + 255) / 256, 256, 0, stream>>>(x, Ap, NNODES * 4, srcA, dstA, fill, ell, NEDGES);

  dim3 g44((NNODES + 63) / 64, 2);   // 4-head GEMMs: BM=64, BN=128
  dim3 g21((NNODES + 63) / 64, 1);   // 1-head GEMM:  BM=64, BN=64
  dim3 gg4((NNODES + 3) / 4, 4);     // per-head gather: 4 nodes/block x 4 heads

  // ---- layer 0 (IN=128 -> 4x64, concat) ----
  k_gemm_mfma<128, 2, 4><<<g44, 256, 0, stream>>>((const ushort*)Ap, (const ushort*)wh0, as0, ad0, h16, vas, vad, NNODES, 256);
  k_gat4h<<<gg4, 256, 0, stream>>>(h16, vas, vad, fill, ell, b0, Ap);

  // ---- layer 1 (256 -> 4x64, concat) ----
  k_gemm_mfma<256, 2, 4><<<g44, 256, 0, stream>>>((const ushort*)Ap, (const ushort*)wh1, as1, ad1, h16, vas, vad, NNODES, 256);
  k_gat4h<<<gg4, 256, 0, stream>>>(h16, vas, vad, fill, ell, b1l, Ap);

  // ---- layer 2 (256 -> 64, 1 head, mean) + MLP ----
  k_gemm_mfma<256, 1, 1><<<g21, 256, 0, stream>>>((const ushort*)Ap, (const ushort*)wh2, as2, ad2, h16, vas, vad, NNODES, 64);
  k_gat1<<<(NNODES + 3) / 4, 256, 0, stream>>>(h16, vas, vad, fill, ell, b2l, w1, mb1, w2, mb2, outp);
}

// Round 17
// 152.410 us; speedup vs baseline: 1.3378x; 1.3378x over previous
//
#include <hip/hip_runtime.h>

#define NNODES 20000
#define NEDGES 320000
#define ELLW 64                           // ELL row width (max degree ~40 for this graph)
#define DCAP 64                           // logit cache == ELL width (no overflow path)

typedef __attribute__((ext_vector_type(4))) float f32x4;
typedef _Float16 f16x4 __attribute__((ext_vector_type(4)));
typedef _Float16 f16x8 __attribute__((ext_vector_type(8)));

__device__ __forceinline__ float leaky(float x) { return x > 0.f ? x : 0.2f * x; }
__device__ __forceinline__ float elu(float x) { return x > 0.f ? x : expm1f(x); }

// async 16B global->LDS (DMA; zero VGPR cost; compiler cannot serialize it)
__device__ __forceinline__ void gll16(const ushort* g, ushort* l) {
  __builtin_amdgcn_global_load_lds((const __attribute__((address_space(1))) void*)g,
                                   (__attribute__((address_space(3))) void*)l, 16, 0, 0);
}

// ---------------- weights -> f16 [OC][K] fragment order; zeroes fill ----------------
__device__ __forceinline__ void prep_w_one(const float* __restrict__ w, _Float16* __restrict__ th,
                                           int K, int OC, int idx) {
  int KC = K / 32;
  int oc = idx / KC, c = idx % KC;
  _Float16 h[32];
#pragma unroll
  for (int r = 0; r < 32; r++) {
    int p = (r < 16) ? ((r >> 2) * 8 + (r & 3)) : (((r - 16) >> 2) * 8 + 4 + (r & 3));
    h[p] = (_Float16)w[(size_t)(c * 32 + r) * OC + oc];
  }
  _Float16* ho = th + (size_t)oc * K + c * 32;
#pragma unroll
  for (int q = 0; q < 4; q++) *(f16x8*)&ho[q * 8] = *(f16x8*)&h[q * 8];
}

__global__ void k_prep_w3z(const float* __restrict__ w0, const float* __restrict__ w1,
                           const float* __restrict__ w2,
                           _Float16* __restrict__ th0, _Float16* __restrict__ th1,
                           _Float16* __restrict__ th2, int* __restrict__ fill) {
  int i = blockIdx.x * blockDim.x + threadIdx.x;
  if (i < NNODES) fill[i] = 0;
  if (i < 1024) prep_w_one(w0, th0, 128, 256, i);
  else if (i < 3072) prep_w_one(w1, th1, 256, 256, i - 1024);
  else if (i < 3584) prep_w_one(w2, th2, 256, 64, i - 3072);
}

// ---------------- fp32 -> f16 fragment-packed + ELL adjacency build (one pass) ----------------
__global__ void k_cvt_ell(const float* __restrict__ a, _Float16* __restrict__ Ap, int total,
                          const int* __restrict__ srcA, const int* __restrict__ dstA,
                          int* __restrict__ fill, int* __restrict__ ell, int e) {
  int i = blockIdx.x * blockDim.x + threadIdx.x;
  if (i < e) {
    int d = dstA[i];
    int k = atomicAdd(&fill[d], 1);
    if (k < ELLW) ell[d * ELLW + k] = srcA[i];
  }
  if (i >= total) return;
  const float* src = a + (size_t)i * 32;
  _Float16 h[32];
#pragma unroll
  for (int r = 0; r < 32; r++) {
    int p = (r < 16) ? ((r >> 2) * 8 + (r & 3)) : (((r - 16) >> 2) * 8 + 4 + (r & 3));
    h[p] = (_Float16)src[r];
  }
  _Float16* ho = Ap + (size_t)i * 32;
#pragma unroll
  for (int q = 0; q < 4; q++) *(f16x8*)&ho[q * 8] = *(f16x8*)&h[q * 8];
}

// ---------------- MFMA GEMM (single f16), async LDS double-buffer, fused asd epilogue ----------------
template <int K, int NCT, int HEADS>
__global__ __launch_bounds__(256) void k_gemm_mfma(const ushort* __restrict__ Ah, const ushort* __restrict__ Bh,
                                                   const float* __restrict__ asrc, const float* __restrict__ adst,
                                                   _Float16* __restrict__ H, float* __restrict__ a_s,
                                                   float* __restrict__ a_d, int M, int OC) {
  constexpr int BM = 64, BN = NCT * 64, NC = K / 32;
  constexpr int BOFF = 2048;
  constexpr int BUFE = BOFF + BN * 32;
  __shared__ ushort sb0[BUFE], sb1[BUFE];
  __shared__ float sh_s[4][64], sh_d[4][64];
  int w = threadIdx.x >> 6, l = threadIdx.x & 63;
  int n0 = blockIdx.x * BM;
  int cw = blockIdx.y * BN + w * (NCT * 16);
  int lr = l & 15;

  int q = l & 3;
  int srow = 16 * w + (l >> 2);
  int sgrow = min(n0 + srow, M - 1);
  int gA = q ^ ((srow >> 1) & 3);
  const ushort* aH = Ah + (size_t)sgrow * K + gA * 8;
  const ushort* bH[NCT];
  int colb[NCT];
#pragma unroll
  for (int i = 0; i < NCT; i++) {
    colb[i] = 16 * NCT * w + 16 * i;
    int sc = colb[i] + (l >> 2);
    int gB = q ^ ((sc >> 1) & 3);
    bH[i] = Bh + (size_t)(blockIdx.y * BN + sc) * K + gB * 8;
  }

#define STAGE(buf, c)                                              \
  {                                                                \
    gll16(aH + (c) * 32, &buf[w * 512]);                           \
    _Pragma("unroll") for (int i = 0; i < NCT; i++)                \
      gll16(bH[i] + (c) * 32, &buf[BOFF + colb[i] * 32]);          \
  }

  f32x4 acc[4][NCT];
#pragma unroll
  for (int r = 0; r < 4; r++)
#pragma unroll
    for (int t = 0; t < NCT; t++) acc[r][t] = (f32x4){0.f, 0.f, 0.f, 0.f};

#define COMP(buf)                                                                   \
  {                                                                                 \
    f16x8 bhf[NCT];                                                                 \
    _Pragma("unroll") for (int t = 0; t < NCT; t++) {                               \
      int bcol = 16 * NCT * w + 16 * t + lr;                                        \
      int gb = (l >> 4) ^ ((bcol >> 1) & 3);                                        \
      bhf[t] = *(const f16x8*)&buf[BOFF + bcol * 32 + gb * 8];                      \
    }                                                                               \
    _Pragma("unroll") for (int r = 0; r < 4; r++) {                                 \
      int arow = 16 * r + lr;                                                       \
      int ga = (l >> 4) ^ ((arow >> 1) & 3);                                        \
      f16x8 ahf = *(const f16x8*)&buf[arow * 32 + ga * 8];                          \
      _Pragma("unroll") for (int t = 0; t < NCT; t++)                               \
        acc[r][t] = __builtin_amdgcn_mfma_f32_16x16x32_f16(ahf, bhf[t], acc[r][t], 0, 0, 0); \
    }                                                                               \
  }

  ushort* cur = sb0;
  ushort* nxt = sb1;
  STAGE(cur, 0);
  __syncthreads();
  for (int c = 0; c < NC; ++c) {
    if (c + 1 < NC) STAGE(nxt, c + 1);
    COMP(cur);
    __syncthreads();
    ushort* tmp = cur; cur = nxt; nxt = tmp;
  }
#undef STAGE
#undef COMP

#pragma unroll
  for (int r = 0; r < 4; r++)
#pragma unroll
    for (int t = 0; t < NCT; t++)
#pragma unroll
      for (int reg = 0; reg < 4; reg++) {
        int row = n0 + 16 * r + (l >> 4) * 4 + reg;
        if (row < M) H[(size_t)row * OC + cw + 16 * t + lr] = (_Float16)acc[r][t][reg];
      }

  float asv[NCT], adv[NCT];
#pragma unroll
  for (int t = 0; t < NCT; t++) {
    asv[t] = asrc[cw + 16 * t + lr];
    adv[t] = adst[cw + 16 * t + lr];
  }
#pragma unroll
  for (int r = 0; r < 4; r++) {
#pragma unroll
    for (int reg = 0; reg < 4; reg++) {
      float ps = 0.f, pd = 0.f;
#pragma unroll
      for (int t = 0; t < NCT; t++) {
        ps += acc[r][t][reg] * asv[t];
        pd += acc[r][t][reg] * adv[t];
      }
#pragma unroll
      for (int mask = 1; mask < 16; mask <<= 1) {
        ps += __shfl_xor(ps, mask, 64);
        pd += __shfl_xor(pd, mask, 64);
      }
      int rl = 16 * r + (l >> 4) * 4 + reg;
      if (lr == 0) { sh_s[w][rl] = ps; sh_d[w][rl] = pd; }
    }
  }
  __syncthreads();
  int tid = threadIdx.x;
  if (HEADS == 4) {
    if (tid < 128) {
      int rr = tid & 63, hl = tid >> 6;
      int row = n0 + rr;
      if (row < M) {
        int hidx = row * 4 + blockIdx.y * 2 + hl;
        a_s[hidx] = sh_s[2 * hl][rr] + sh_s[2 * hl + 1][rr];
        a_d[hidx] = sh_d[2 * hl][rr] + sh_d[2 * hl + 1][rr];
      }
    }
  } else {
    if (tid < 64) {
      int row = n0 + tid;
      if (row < M) {
        a_s[row] = sh_s[0][tid] + sh_s[1][tid] + sh_s[2][tid] + sh_s[3][tid];
        a_d[row] = sh_d[0][tid] + sh_d[1][tid] + sh_d[2][tid] + sh_d[3][tid];
      }
    }
  }
}

// ---------------- fused softmax + gather (4 heads): ELL rows, alpha precomputed in LDS ----------------
// Phase 1: lanes (head=l>>4, sub=l&15) cache logits + online (m,s).
// Phase 1.5: convert cached logits to alpha in place (one exp per edge-head — the minimum).
// Phase 2: lane = (half=l>>5, sl=l&31) f16x8 channels; halves take edges j, j+1; NO exp in loop.
__global__ __launch_bounds__(256) void k_gat4(const _Float16* __restrict__ h, const float* __restrict__ a_s,
                                              const float* __restrict__ a_d, const int* __restrict__ fill,
                                              const int* __restrict__ ell, const float* __restrict__ bias,
                                              _Float16* __restrict__ Ap) {
  __shared__ float elds[4][DCAP * 4];
  int wid = threadIdx.x >> 6, l = threadIdx.x & 63;
  int n = blockIdx.x * 4 + wid;
  if (n >= NNODES) return;
  int head = l >> 4, sub = l & 15;
  int half = l >> 5, sl = l & 31;
  int head2 = sl >> 3;
  int jb = n * ELLW;
  int cnt = min(fill[n], ELLW);
  int je = jb + cnt;
  float ad = a_d[n * 4 + head];
  float es = leaky(a_s[n * 4 + head] + ad);
  float m = -1e30f, s = 0.f;
  if (sub == 0) { m = es; s = 1.f; }
  for (int j = jb + sub; j < je; j += 16) {
    float e = leaky(a_s[ell[j] * 4 + head] + ad);
    elds[wid][(j - jb) * 4 + head] = e;
    float nm = fmaxf(m, e);
    s = s * __expf(m - nm) + __expf(e - nm);
    m = nm;
  }
#pragma unroll
  for (int mask = 1; mask < 16; mask <<= 1) {
    float m2 = __shfl_xor(m, mask, 64);
    float s2 = __shfl_xor(s, mask, 64);
    float nm = fmaxf(m, m2);
    s = s * __expf(m - nm) + s2 * __expf(m2 - nm);
    m = nm;
  }
  __asm__ volatile("" ::: "memory");
  float inv = 1.f / s;
  float sa = __expf(es - m) * inv;
  // phase 1.5: logits -> alpha in place (one exp per edge-head total)
  for (int j = jb + sub; j < je; j += 16) {
    int o = (j - jb) * 4 + head;
    elds[wid][o] = __expf(elds[wid][o] - m) * inv;
  }
  int srcl = head2 << 4;
  float sa2 = __shfl(sa, srcl, 64);
  __asm__ volatile("" ::: "memory");

  float acc[8];
  f16x8 hv = *(const f16x8*)&h[(size_t)n * 256 + sl * 8];
#pragma unroll
  for (int i = 0; i < 8; i++) acc[i] = (half == 0) ? sa2 * (float)hv[i] : 0.f;

  int j = jb;
  for (; j + 7 < je; j += 8) {   // 4 pairs -> 8 edges in flight; pure load+FMA
    int e0 = j + half, e1 = j + 2 + half, e2 = j + 4 + half, e3 = j + 6 + half;
    int s0 = ell[e0], s1 = ell[e1], s2 = ell[e2], s3 = ell[e3];
    float a0 = elds[wid][(e0 - jb) * 4 + head2];
    float a1 = elds[wid][(e1 - jb) * 4 + head2];
    float a2 = elds[wid][(e2 - jb) * 4 + head2];
    float a3 = elds[wid][(e3 - jb) * 4 + head2];
    f16x8 v0 = *(const f16x8*)&h[(size_t)s0 * 256 + sl * 8];
    f16x8 v1 = *(const f16x8*)&h[(size_t)s1 * 256 + sl * 8];
    f16x8 v2 = *(const f16x8*)&h[(size_t)s2 * 256 + sl * 8];
    f16x8 v3 = *(const f16x8*)&h[(size_t)s3 * 256 + sl * 8];
#pragma unroll
    for (int i = 0; i < 8; i++)
      acc[i] += a0 * (float)v0[i] + a1 * (float)v1[i] + a2 * (float)v2[i] + a3 * (float)v3[i];
  }
  for (; j + 1 < je; j += 2) {
    int e0 = j + half;
    int s0 = ell[e0];
    float a0 = elds[wid][(e0 - jb) * 4 + head2];
    f16x8 v0 = *(const f16x8*)&h[(size_t)s0 * 256 + sl * 8];
#pragma unroll
    for (int i = 0; i < 8; i++) acc[i] += a0 * (float)v0[i];
  }
  if (j < je) {   // unpaired final edge: half 0 only
    int s0 = ell[j];
    float a0 = (half == 0) ? elds[wid][(j - jb) * 4 + head2] : 0.f;
    f16x8 v0 = *(const f16x8*)&h[(size_t)s0 * 256 + sl * 8];
#pragma unroll
    for (int i = 0; i < 8; i++) acc[i] += a0 * (float)v0[i];
  }
#pragma unroll
  for (int i = 0; i < 8; i++) acc[i] += __shfl_xor(acc[i], 32, 64);

  // epilogue: lane stores channels c0 = sl*8 + half*4 as packed f16 for next GEMM
  int c0 = sl * 8 + half * 4;
  int k = c0 & 31;
  size_t base = (size_t)n * 256 + (c0 >> 5) * 32 + ((k < 16) ? (k >> 2) * 8 : (((k - 16) >> 2) * 8 + 4));
  float4 b = *(const float4*)&bias[c0];
  int ai = half * 4;
  f16x4 pk;
  pk[0] = (_Float16)elu(acc[ai + 0] + b.x);
  pk[1] = (_Float16)elu(acc[ai + 1] + b.y);
  pk[2] = (_Float16)elu(acc[ai + 2] + b.z);
  pk[3] = (_Float16)elu(acc[ai + 3] + b.w);
  *(f16x4*)&Ap[base] = pk;
}

// ---------------- fused softmax + gather + MLP (1 head): alpha precomputed in LDS ----------------
__global__ __launch_bounds__(256) void k_gat1(const _Float16* __restrict__ h, const float* __restrict__ a_s,
                                              const float* __restrict__ a_d, const int* __restrict__ fill,
                                              const int* __restrict__ ell, const float* __restrict__ bias,
                                              const float* __restrict__ w1, const float* __restrict__ b1,
                                              const float* __restrict__ w2, const float* __restrict__ b2,
                                              float* __restrict__ out) {
  __shared__ float elds[4][DCAP];
  __shared__ float sh[4][64];
  int wid = threadIdx.x >> 6, l = threadIdx.x & 63;
  int n = blockIdx.x * 4 + wid;
  int grp = l >> 4, cl = l & 15;
  float acc[4] = {0.f, 0.f, 0.f, 0.f};
  if (n < NNODES) {
    int jb = n * ELLW;
    int cnt = min(fill[n], ELLW);
    int je = jb + cnt;
    float ad = a_d[n];
    float es = leaky(a_s[n] + ad);
    float m = -1e30f, s = 0.f;
    if (l == 0) { m = es; s = 1.f; }
    for (int j = jb + l; j < je; j += 64) {
      float e = leaky(a_s[ell[j]] + ad);
      elds[wid][j - jb] = e;
      float nm = fmaxf(m, e);
      s = s * __expf(m - nm) + __expf(e - nm);
      m = nm;
    }
#pragma unroll
    for (int mask = 1; mask < 64; mask <<= 1) {
      float m2 = __shfl_xor(m, mask, 64);
      float s2 = __shfl_xor(s, mask, 64);
      float nm = fmaxf(m, m2);
      s = s * __expf(m - nm) + s2 * __expf(m2 - nm);
      m = nm;
    }
    __asm__ volatile("" ::: "memory");
    float inv = 1.f / s;
    float sa = __expf(es - m) * inv;
    // phase 1.5: logits -> alpha in place
    for (int j = jb + l; j < je; j += 64)
      elds[wid][j - jb] = __expf(elds[wid][j - jb] - m) * inv;
    __asm__ volatile("" ::: "memory");
    f16x4 hv = *(const f16x4*)&h[(size_t)n * 64 + cl * 4];
    if (grp == 0) {
#pragma unroll
      for (int i = 0; i < 4; i++) acc[i] = sa * (float)hv[i];
    }
    int j = jb;
    for (; j + 7 < je; j += 8) {
      int e0 = j + grp, e1 = j + 4 + grp;
      int s0 = ell[e0], s1 = ell[e1];
      float a0 = elds[wid][e0 - jb];
      float a1 = elds[wid][e1 - jb];
      f16x4 v0 = *(const f16x4*)&h[(size_t)s0 * 64 + cl * 4];
      f16x4 v1 = *(const f16x4*)&h[(size_t)s1 * 64 + cl * 4];
#pragma unroll
      for (int i = 0; i < 4; i++) acc[i] += a0 * (float)v0[i] + a1 * (float)v1[i];
    }
    for (; j + 3 < je; j += 4) {
      int e0 = j + grp;
      int s0 = ell[e0];
      float a0 = elds[wid][e0 - jb];
      f16x4 v0 = *(const f16x4*)&h[(size_t)s0 * 64 + cl * 4];
#pragma unroll
      for (int i = 0; i < 4; i++) acc[i] += a0 * (float)v0[i];
    }
    if (j + grp < je) {
      int e0 = j + grp;
      int s0 = ell[e0];
      float a0 = elds[wid][e0 - jb];
      f16x4 v0 = *(const f16x4*)&h[(size_t)s0 * 64 + cl * 4];
#pragma unroll
      for (int i = 0; i < 4; i++) acc[i] += a0 * (float)v0[i];
    }
  }
#pragma unroll
  for (int i = 0; i < 4; i++) {
    acc[i] += __shfl_xor(acc[i], 16, 64);
    acc[i] += __shfl_xor(acc[i], 32, 64);
  }
  if (n < NNODES && l < 16) {
#pragma unroll
    for (int i = 0; i < 4; i++) sh[wid][cl * 4 + i] = elu(acc[i] + bias[cl * 4 + i]);
  }
  __syncthreads();
  float r = 0.f;
  if (l < 32 && n < NNODES) {
    r = b1[l];
#pragma unroll 8
    for (int k = 0; k < 64; k++) r += sh[wid][k] * w1[k * 32 + l];
    r = fmaxf(r, 0.f);
    r *= w2[l];
  }
  for (int mask = 16; mask >= 1; mask >>= 1) r += __shfl_xor(r, mask, 64);
  if (l == 0 && n < NNODES) out[n] = r + b2[0];
}

extern "C" void kernel_launch(void* const* d_in, const int* in_sizes, int n_in,
                              void* d_out, int out_size, void* d_ws, size_t ws_size,
                              hipStream_t stream) {
  const float* x    = (const float*)d_in[0];
  const int*   eidx = (const int*)d_in[1];
  const float* lin0 = (const float*)d_in[2];
  const float* as0  = (const float*)d_in[3];
  const float* ad0  = (const float*)d_in[4];
  const float* b0   = (const float*)d_in[5];
  const float* lin1 = (const float*)d_in[6];
  const float* as1  = (const float*)d_in[7];
  const float* ad1  = (const float*)d_in[8];
  const float* b1l  = (const float*)d_in[9];
  const float* lin2 = (const float*)d_in[10];
  const float* as2  = (const float*)d_in[11];
  const float* ad2  = (const float*)d_in[12];
  const float* b2l  = (const float*)d_in[13];
  const float* w1   = (const float*)d_in[14];
  const float* mb1  = (const float*)d_in[15];
  const float* w2   = (const float*)d_in[16];
  const float* mb2  = (const float*)d_in[17];
  float* outp = (float*)d_out;

  const int* srcA = eidx;
  const int* dstA = eidx + NEDGES;

  char* ws = (char*)d_ws;
  size_t o = 0;
  auto alloc = [&](size_t bytes) { size_t r = o; o += (bytes + 255) & ~255UL; return r; };
  _Float16* h16 = (_Float16*)(ws + alloc((size_t)NNODES * 256 * 2));
  _Float16* Ap  = (_Float16*)(ws + alloc((size_t)NNODES * 256 * 2));
  _Float16* wh0 = (_Float16*)(ws + alloc(128 * 256 * 2));
  _Float16* wh1 = (_Float16*)(ws + alloc(256 * 256 * 2));
  _Float16* wh2 = (_Float16*)(ws + alloc(256 * 64 * 2));
  float*  vas = (float*)(ws + alloc((size_t)NNODES * 4 * 4));
  float*  vad = (float*)(ws + alloc((size_t)NNODES * 4 * 4));
  int* fill = (int*)(ws + alloc(NNODES * 4));
  int* ell  = (int*)(ws + alloc((size_t)NNODES * ELLW * 4));

  // prep: weight pack + fill zero, then x pack + ELL adjacency build (2 dispatches total)
  k_prep_w3z<<<(NNODES + 255) / 256, 256, 0, stream>>>(lin0, lin1, lin2, wh0, wh1, wh2, fill);
  k_cvt_ell<<<(NEDGES + 255) / 256, 256, 0, stream>>>(x, Ap, NNODES * 4, srcA, dstA, fill, ell, NEDGES);

  dim3 g44((NNODES + 63) / 64, 2);   // 4-head GEMMs: BM=64, BN=128
  dim3 g21((NNODES + 63) / 64, 1);   // 1-head GEMM:  BM=64, BN=64

  // ---- layer 0 (IN=128 -> 4x64, concat) ----
  k_gemm_mfma<128, 2, 4><<<g44, 256, 0, stream>>>((const ushort*)Ap, (const ushort*)wh0, as0, ad0, h16, vas, vad, NNODES, 256);
  k_gat4<<<5000, 256, 0, stream>>>(h16, vas, vad, fill, ell, b0, Ap);

  // ---- layer 1 (256 -> 4x64, concat) ----
  k_gemm_mfma<256, 2, 4><<<g44, 256, 0, stream>>>((const ushort*)Ap, (const ushort*)wh1, as1, ad1, h16, vas, vad, NNODES, 256);
  k_gat4<<<5000, 256, 0, stream>>>(h16, vas, vad, fill, ell, b1l, Ap);

  // ---- layer 2 (256 -> 64, 1 head, mean) + MLP ----
  k_gemm_mfma<256, 1, 1><<<g21, 256, 0, stream>>>((const ushort*)Ap, (const ushort*)wh2, as2, ad2, h16, vas, vad, NNODES, 64);
  k_gat1<<<5000, 256, 0, stream>>>(h16, vas, vad, fill, ell, b2l, w1, mb1, w2, mb2, outp);
}